// Round 8
// baseline (296.896 us; speedup 1.0000x reference)
//
#include <hip/hip_runtime.h>
#include <stdint.h>

#define B_  4
#define S_  2048
#define D_  1024
#define H_  16
#define DH_ 64

#define LOG2E 1.44269504088896340736f

typedef short bf16x8 __attribute__((ext_vector_type(8)));
typedef float f32x4v __attribute__((ext_vector_type(4)));
typedef float f32x16 __attribute__((ext_vector_type(16)));
typedef unsigned short u16x4 __attribute__((ext_vector_type(4)));
typedef unsigned short u16x8 __attribute__((ext_vector_type(8)));

typedef const __attribute__((address_space(1))) uint32_t GAS;
typedef __attribute__((address_space(3))) uint32_t LAS;

__device__ __forceinline__ void gload16(const void* g, void* l){
  __builtin_amdgcn_global_load_lds((GAS*)g, (LAS*)l, 16, 0, 0);
}

__device__ __forceinline__ unsigned short f2bf(float x){
  union { float f; uint32_t u; } v; v.f = x;
  uint32_t r = v.u + 0x7fffu + ((v.u >> 16) & 1u);
  return (unsigned short)(r >> 16);
}

__device__ __forceinline__ uint32_t cvtpk(float lo, float hi_){
  uint32_t r;
  asm("v_cvt_pk_bf16_f32 %0, %1, %2" : "=v"(r) : "v"(lo), "v"(hi_));
  return r;
}

__device__ __forceinline__ void plswap(uint32_t& a, uint32_t& b){
  asm volatile("v_permlane32_swap_b32 %0, %1" : "+v"(a), "+v"(b));
}

// ---------------------------------------------------------------- fp32 -> bf16 (hs + 3 weights)
__global__ void cvt_all(const float* __restrict__ hs, const float* __restrict__ Wq,
                        const float* __restrict__ Wk, const float* __restrict__ Wv,
                        unsigned short* __restrict__ hsb, unsigned short* __restrict__ Wqb,
                        unsigned short* __restrict__ Wkb, unsigned short* __restrict__ Wvb){
  const int z = blockIdx.y;
  const float* src = (z==0)?hs:(z==1)?Wq:(z==2)?Wk:Wv;
  unsigned short* dst = (z==0)?hsb:(z==1)?Wqb:(z==2)?Wkb:Wvb;
  const int n8 = (z==0) ? 1048576 : 131072;
  int i = blockIdx.x * blockDim.x + threadIdx.x;
  if (i >= n8) return;
  const float4* s = (const float4*)src + (size_t)i*2;
  float4 a = s[0], b = s[1];
  u16x8 o;
  o[0]=f2bf(a.x); o[1]=f2bf(a.y); o[2]=f2bf(a.z); o[3]=f2bf(a.w);
  o[4]=f2bf(b.x); o[5]=f2bf(b.y); o[6]=f2bf(b.z); o[7]=f2bf(b.w);
  *((u16x8*)dst + i) = o;
}

// ---------------------------------------------------------------- mask -> SC-layout table (pre-scaled by log2e)
__global__ void mask_sc(const float* __restrict__ mask, float* __restrict__ mskT){
  int idx = blockIdx.x * blockDim.x + threadIdx.x;
  if (idx >= B_*32*2*32) return;
  int b = idx >> 11, rem = idx & 2047;
  int j = rem >> 6, hi = (rem >> 5) & 1, v = rem & 31;
  int r = v & 15, t = v >> 4;
  int key = (r & 3) + ((r >> 2) << 3) + (hi << 2) + (t << 5);
  mskT[idx] = mask[b * S_ + j * 64 + key] * LOG2E;
}

// ---------------------------------------------------------------- QKV GEMM, 128x256 tile
// out[m,n] = sum_k hs[m,k]*W[n,k] + bias[n].  BK=64, 8 waves (2x4) x 64x64 sub-tiles.
// Traffic-bound diagnosis (r2/r4/r7 invariance): bigger tile halves staged B-bytes per
// output. Single-buffered r4-proven 2-barrier loop; 48KB LDS -> 2 blocks/CU.
// z<2 (Q,K): acc = mfma(W_frag, hs_frag) -> lane holds 4 consecutive dh at one token.
// z==2 (V):  acc = mfma(hs_frag, W_frag) -> lane holds 4 consecutive tokens at one dh.
__global__ __launch_bounds__(512) void qkv_gemm(
    const unsigned short* __restrict__ hsb,
    const unsigned short* __restrict__ Wqb,
    const unsigned short* __restrict__ Wkb,
    const unsigned short* __restrict__ Wvb,
    const float* __restrict__ bq, const float* __restrict__ bk,
    const float* __restrict__ bv,
    unsigned short* __restrict__ Qb, unsigned short* __restrict__ Kb,
    unsigned short* __restrict__ Vt)
{
  __shared__ char As[16384];   // [128 rows][64 bf16 = 128B], linear
  __shared__ char Bs[32768];   // [256 rows][64 bf16 = 128B], linear

  const int tid  = threadIdx.x;
  const int z    = blockIdx.z;
  const unsigned short* Wsel = (z==0) ? Wqb : (z==1) ? Wkb : Wvb;
  const float*          bias = (z==0) ? bq  : (z==1) ? bk  : bv;
  const int bm = blockIdx.x * 128, bn = blockIdx.y * 256;
  const int lane = tid & 63, wave = tid >> 6;
  const int g = lane >> 4, c = lane & 15;
  const int wr = wave >> 2, wc = wave & 3;

  f32x4v acc[4][4];
  #pragma unroll
  for (int i=0;i<4;++i)
    #pragma unroll
    for (int j=0;j<4;++j) acc[i][j] = (f32x4v){0.f,0.f,0.f,0.f};

  const int srow = lane >> 3;          // 0..7 within 1KB chunk
  const int scol = (lane & 7) << 4;    // byte col within 128B row

  for (int kt=0; kt<16; ++kt){
    const int k0b = kt*128;
    // A: 16 KB = 16 chunks of 8 rows; wave stages 2
    #pragma unroll
    for (int cc=0; cc<2; ++cc){
      const int rb = wave*16 + cc*8;
      gload16((const char*)hsb  + (size_t)(bm+rb+srow)*2048 + k0b + scol, &As[rb*128]);
    }
    // B: 32 KB = 32 chunks of 8 rows; wave stages 4
    #pragma unroll
    for (int cc=0; cc<4; ++cc){
      const int rb = wave*32 + cc*8;
      gload16((const char*)Wsel + (size_t)(bn+rb+srow)*2048 + k0b + scol, &Bs[rb*128]);
    }
    __syncthreads();
    #pragma unroll
    for (int ks=0; ks<2; ++ks){
      bf16x8 af[4], bfr[4];
      #pragma unroll
      for (int mt=0;mt<4;++mt){
        int row = wr*64 + mt*16 + c;
        af[mt] = *(const bf16x8*)&As[row*128 + ks*64 + g*16];
      }
      #pragma unroll
      for (int nt=0;nt<4;++nt){
        int row = wc*64 + nt*16 + c;
        bfr[nt] = *(const bf16x8*)&Bs[row*128 + ks*64 + g*16];
      }
      if (z == 2){
        #pragma unroll
        for (int mt=0;mt<4;++mt)
          #pragma unroll
          for (int nt=0;nt<4;++nt)
            acc[mt][nt] = __builtin_amdgcn_mfma_f32_16x16x32_bf16(
                            af[mt], bfr[nt], acc[mt][nt], 0, 0, 0);
      } else {
        #pragma unroll
        for (int mt=0;mt<4;++mt)
          #pragma unroll
          for (int nt=0;nt<4;++nt)
            acc[mt][nt] = __builtin_amdgcn_mfma_f32_16x16x32_bf16(
                            bfr[nt], af[mt], acc[mt][nt], 0, 0, 0);
      }
    }
    __syncthreads();
  }

  if (z == 2){
    #pragma unroll
    for (int nt=0;nt<4;++nt){
      int n = bn + wc*64 + nt*16 + c;
      float bb = bias[n];
      int h = n >> 6, dh = n & 63;
      #pragma unroll
      for (int mt=0;mt<4;++mt){
        int m0 = bm + wr*64 + mt*16 + g*4;
        int bi = m0 >> 11, s0 = m0 & 2047;
        u16x4 o;
        #pragma unroll
        for (int r=0;r<4;++r) o[r] = f2bf(acc[mt][nt][r] + bb);
        *(u16x4*)(Vt + ((size_t)((bi*H_ + h)*DH_ + dh))*S_ + s0) = o;
      }
    }
  } else {
    const float qscale = (z==0) ? 0.125f*LOG2E : 1.0f;
    unsigned short* dst = (z==0) ? Qb : Kb;
    #pragma unroll
    for (int nt=0;nt<4;++nt){
      int n0 = bn + wc*64 + nt*16 + g*4;          // dh-dim, 4 consecutive per lane
      f32x4v bb4 = *(const f32x4v*)&bias[n0];
      int h = n0 >> 6, dh0 = n0 & 63;
      #pragma unroll
      for (int mt=0;mt<4;++mt){
        int m = bm + wr*64 + mt*16 + c;           // token
        int bi = m >> 11, s = m & 2047;
        u16x4 o;
        #pragma unroll
        for (int r=0;r<4;++r) o[r] = f2bf((acc[mt][nt][r] + bb4[r]) * qscale);
        *(u16x4*)(dst + ((size_t)((bi*H_ + h)*S_ + s))*DH_ + dh0) = o;
      }
    }
  }
}

// ---------------------------------------------------------------- fused attention, swapped-QK^T 32x32
// FROZEN round-4/7 version (passed 3x, 104us): 8 waves x 64 q = 512 q/block, grid 256.
// Frag-major conflict-free LDS; mask in MFMA C-init; exp2 softmax (Q pre-scaled by
// 0.125*log2e); P built in-register via cvt_pk + permlane32_swap.
__global__ __launch_bounds__(512, 2) void attn_fwd(
    const unsigned short* __restrict__ Qb,
    const unsigned short* __restrict__ Kb,
    const unsigned short* __restrict__ Vt,
    const float* __restrict__ mskT,
    float* __restrict__ out)
{
  __shared__ char Ks[2][8192];
  __shared__ char Vs[2][8192];

  const int tid  = threadIdx.x;
  const int wave = tid >> 6, lane = tid & 63;
  const int q32 = lane & 31, hi = lane >> 5;

  // XCD swizzle: all 4 q-blocks of a (b,h) group land on one XCD; 8 groups/XCD.
  const int raw = blockIdx.x;                  // 0..255
  const int grp = (raw & 7) * 8 + (raw >> 5);
  const int sub = (raw >> 3) & 3;
  const int b = grp >> 4, h = grp & 15;
  const int qbase = sub * 512 + wave * 64;

  const unsigned short* Qh = Qb + (size_t)(b*H_ + h)*S_*DH_;
  const unsigned short* Kh = Kb + (size_t)(b*H_ + h)*S_*DH_;
  const unsigned short* Vh = Vt + (size_t)(b*H_ + h)*DH_*S_;

  // Q fragments (held whole kernel): qf[qc][dc] = B-operand (col=q, k = d)
  bf16x8 qf[2][4];
  #pragma unroll
  for (int qc=0;qc<2;++qc)
    #pragma unroll
    for (int dc=0;dc<4;++dc)
      qf[qc][dc] = *(const bf16x8*)(Qh + (size_t)(qbase + qc*32 + q32)*DH_ + dc*16 + hi*8);

  f32x16 O[2][2];
  #pragma unroll
  for (int qc=0;qc<2;++qc)
    #pragma unroll
    for (int df=0;df<2;++df)
      #pragma unroll
      for (int e=0;e<16;++e) O[qc][df][e] = 0.f;
  float lsum[2] = {0.f, 0.f};

  // staging: wave w stages frag chunk w of both K and V tiles.
  // K chunk w=(t*4+dc): lane l -> key t*32+(l&31), d-bytes dc*32+(l>>5)*16
  // V chunk w=(df*4+kc): lane l -> d-row df*32+(l&31), key-bytes kc*32+(l>>5)*16
  const char* Ksrc = (const char*)Kh + (size_t)((wave>>2)*32 + q32)*128 + (wave&3)*32 + hi*16;
  const char* Vsrc = (const char*)Vh + (size_t)((wave>>2)*32 + q32)*4096 + (wave&3)*32 + hi*16;

  gload16(Ksrc, &Ks[0][wave*1024]);
  gload16(Vsrc, &Vs[0][wave*1024]);
  __syncthreads();

  const float* mrow = mskT + b*2048 + hi*32;

  for (int j=0;j<32;++j){
    const int bb = j & 1;
    if (j < 31){
      gload16(Ksrc + (size_t)(j+1)*64*128, &Ks[bb^1][wave*1024]);
      gload16(Vsrc + (size_t)(j+1)*64*2,   &Vs[bb^1][wave*1024]);
    }
    const char* Kt = Ks[bb];
    const char* Vl = Vs[bb];

    // SC init = mask (already * log2e); same init for both qc.
    const float* mj = mrow + j*64;
    f32x16 SC[2][2];
    #pragma unroll
    for (int t=0;t<2;++t){
      f32x4v m0 = *(const f32x4v*)(mj + t*16 + 0);
      f32x4v m1 = *(const f32x4v*)(mj + t*16 + 4);
      f32x4v m2 = *(const f32x4v*)(mj + t*16 + 8);
      f32x4v m3 = *(const f32x4v*)(mj + t*16 + 12);
      #pragma unroll
      for (int r=0;r<16;++r){
        const float mval = (r<4) ? m0[r&3] : (r<8) ? m1[r&3] : (r<12) ? m2[r&3] : m3[r&3];
        SC[0][t][r] = mval;
        SC[1][t][r] = mval;
      }
    }

    // QK^T: SC[qc][t] += K_frag x Q_frag  (scores already in log2 domain)
    __builtin_amdgcn_s_setprio(1);
    #pragma unroll
    for (int t=0;t<2;++t){
      #pragma unroll
      for (int dc=0;dc<4;++dc){
        bf16x8 kf = *(const bf16x8*)&Kt[((t*4+dc)<<10) + lane*16];
        SC[0][t] = __builtin_amdgcn_mfma_f32_32x32x16_bf16(kf, qf[0][dc], SC[0][t], 0,0,0);
        SC[1][t] = __builtin_amdgcn_mfma_f32_32x32x16_bf16(kf, qf[1][dc], SC[1][t], 0,0,0);
      }
    }
    __builtin_amdgcn_s_setprio(0);

    // p = exp2(score), accumulate row-sum partials
    #pragma unroll
    for (int t=0;t<2;++t)
      #pragma unroll
      for (int r=0;r<16;++r){
        float p0 = __builtin_amdgcn_exp2f(SC[0][t][r]);
        float p1 = __builtin_amdgcn_exp2f(SC[1][t][r]);
        SC[0][t][r] = p0; SC[1][t][r] = p1;
        lsum[0] += p0; lsum[1] += p1;
      }

    // PV per 16-key chunk: build P B-frags in-register, O += mfma(V^T_frag, P)
    #pragma unroll
    for (int kc=0;kc<4;++kc){
      const int t = kc>>1, rb = (kc&1)*8;
      uint32_t w[2][4];
      #pragma unroll
      for (int qc=0;qc<2;++qc){
        uint32_t a  = cvtpk(SC[qc][t][rb+0], SC[qc][t][rb+1]);
        uint32_t b2 = cvtpk(SC[qc][t][rb+4], SC[qc][t][rb+5]);
        uint32_t c2 = cvtpk(SC[qc][t][rb+2], SC[qc][t][rb+3]);
        uint32_t d2 = cvtpk(SC[qc][t][rb+6], SC[qc][t][rb+7]);
        plswap(a, b2);
        plswap(c2, d2);
        w[qc][0]=a; w[qc][1]=c2; w[qc][2]=b2; w[qc][3]=d2;
      }
      union PAU { uint32_t u[4]; bf16x8 v; };
      PAU pa0, pa1;
      pa0.u[0]=w[0][0]; pa0.u[1]=w[0][1]; pa0.u[2]=w[0][2]; pa0.u[3]=w[0][3];
      pa1.u[0]=w[1][0]; pa1.u[1]=w[1][1]; pa1.u[2]=w[1][2]; pa1.u[3]=w[1][3];
      __builtin_amdgcn_s_setprio(1);
      #pragma unroll
      for (int df=0;df<2;++df){
        bf16x8 vf = *(const bf16x8*)&Vl[((df*4+kc)<<10) + lane*16];
        O[0][df] = __builtin_amdgcn_mfma_f32_32x32x16_bf16(vf, pa0.v, O[0][df], 0,0,0);
        O[1][df] = __builtin_amdgcn_mfma_f32_32x32x16_bf16(vf, pa1.v, O[1][df], 0,0,0);
      }
      __builtin_amdgcn_s_setprio(0);
    }
    __syncthreads();
  }

  // epilogue: merge half-wave partial sums, normalize, store
  #pragma unroll
  for (int qc=0;qc<2;++qc){
    uint32_t x = __float_as_uint(lsum[qc]), y = x;
    plswap(x, y);
    const float inv = 1.0f / (__uint_as_float(x) + __uint_as_float(y));
    const int q = qbase + qc*32 + q32;
    float* orow = out + ((size_t)b*S_ + q)*D_ + h*DH_;
    #pragma unroll
    for (int df=0;df<2;++df)
      #pragma unroll
      for (int rg=0;rg<4;++rg){
        float4 v4;
        v4.x = O[qc][df][rg*4+0]*inv;
        v4.y = O[qc][df][rg*4+1]*inv;
        v4.z = O[qc][df][rg*4+2]*inv;
        v4.w = O[qc][df][rg*4+3]*inv;
        *(float4*)&orow[df*32 + rg*8 + hi*4] = v4;
      }
  }
}

// ---------------------------------------------------------------- launch
extern "C" void kernel_launch(void* const* d_in, const int* in_sizes, int n_in,
                              void* d_out, int out_size, void* d_ws, size_t ws_size,
                              hipStream_t stream)
{
  (void)in_sizes; (void)n_in; (void)out_size; (void)ws_size;
  const float* hs   = (const float*)d_in[0];
  const float* mask = (const float*)d_in[1];
  const float* Wq   = (const float*)d_in[2];
  const float* bq   = (const float*)d_in[3];
  const float* Wk   = (const float*)d_in[4];
  const float* bk   = (const float*)d_in[5];
  const float* Wv   = (const float*)d_in[6];
  const float* bv   = (const float*)d_in[7];
  float* out = (float*)d_out;

  char* ws = (char*)d_ws;
  unsigned short* hsb = (unsigned short*)(ws);              // 16 MB
  unsigned short* Wqb = (unsigned short*)(ws + 16777216);   //  2 MB
  unsigned short* Wkb = (unsigned short*)(ws + 18874368);   //  2 MB
  unsigned short* Wvb = (unsigned short*)(ws + 20971520);   //  2 MB
  unsigned short* Qb  = (unsigned short*)(ws + 23068672);   // 16 MB [B,H,S,DH]
  unsigned short* Kb  = (unsigned short*)(ws + 39845888);   // 16 MB [B,H,S,DH]
  unsigned short* Vt  = (unsigned short*)(ws + 56623104);   // 16 MB [B,H,DH,S]
  float*          mskT= (float*)(ws + 73400320);            // 32 KB SC-layout mask

  cvt_all<<<dim3(4096, 4), 256, 0, stream>>>(hs, Wq, Wk, Wv, hsb, Wqb, Wkb, Wvb);
  mask_sc<<<32, 256, 0, stream>>>(mask, mskT);

  qkv_gemm<<<dim3(64, 4, 3), 512, 0, stream>>>(
      hsb, Wqb, Wkb, Wvb, bq, bk, bv, Qb, Kb, Vt);

  attn_fwd<<<256, 512, 0, stream>>>(Qb, Kb, Vt, mskT, out);
}